// Round 6
// baseline (508.302 us; speedup 1.0000x reference)
//
#include <hip/hip_runtime.h>

#define N_NODES 50000
#define N_ENT   100000
#define N_REL   16
#define DIM     128
#define E_EDGES 600000
#define NQ      8192
#define PATH_DIM 5
#define NK      (N_NODES * N_REL)        /* 800000 (rel,dst) segments, rel-major */
#define KTOT    (N_REL * DIM + DIM)      /* 2176 */
#define NG      (KTOT / 32)              /* 68 k-groups of 32 */
#define BM      64                       /* fused-layer block rows */

typedef __attribute__((ext_vector_type(8))) short short8;
typedef __attribute__((ext_vector_type(4))) float floatx4;

static __device__ __forceinline__ short f2bf(float x) {
  unsigned u = __builtin_bit_cast(unsigned, x);
  u = (u + 0x7FFFu + ((u >> 16) & 1u)) >> 16;   // RNE
  return (short)u;
}
static __device__ __forceinline__ float bf_lo(unsigned u) {
  return __builtin_bit_cast(float, u << 16);
}
static __device__ __forceinline__ float bf_hi(unsigned u) {
  return __builtin_bit_cast(float, u & 0xffff0000u);
}
static __device__ __forceinline__ unsigned pk2(float a, float b) {
  return (unsigned)(unsigned short)f2bf(a) | ((unsigned)(unsigned short)f2bf(b) << 16);
}

// ---------- single-pass bucketing: capacity-4 direct slots + overflow chain ----------
// cnt[key]  : per-(rel,dst) edge count
// slots     : first 4 edge srcs per key (order irrelevant for a sum)
// head/ovf_*: linked chain of the (rare, ~0.1%) edges beyond 4; 0 = null (ids 1-based)
__global__ void k_bucket(const int* __restrict__ ei, const int* __restrict__ et,
                         int* __restrict__ cnt, int* __restrict__ head,
                         int* __restrict__ cursor, int* __restrict__ slots,
                         int* __restrict__ ovf_src, int* __restrict__ ovf_next) {
  int e = blockIdx.x * 256 + threadIdx.x;
  if (e >= E_EDGES) return;
  int src = ei[e];
  int key = et[e] * N_NODES + ei[E_EDGES + e];
  int pos = atomicAdd(&cnt[key], 1);
  if (pos < 4) {
    slots[(size_t)key * 4 + pos] = src;
  } else {
    int nid = atomicAdd(cursor, 1) + 1;          // 1-based, 0 == null
    ovf_src[nid] = src;
    ovf_next[nid] = atomicExch(&head[key], nid);
  }
}

// ---------- h0 gather (fp32 emb -> bf16 h) ----------
__global__ void k_h0(const int* __restrict__ nid, const float* __restrict__ emb,
                     unsigned* __restrict__ h) {
  int g = blockIdx.x * 256 + threadIdx.x;     // over N*32
  int n = g >> 5;
  int q = g & 31;
  float4 v = *(const float4*)(emb + (size_t)nid[n] * DIM + q * 4);
  uint2 pk;
  pk.x = pk2(v.x, v.y);
  pk.y = pk2(v.z, v.w);
  *(uint2*)(h + (size_t)n * 64 + q * 2) = pk;
}

// ---------- weights -> bf16 fragment tiles ----------
// layout: [l][g=k/32][nt8=n/16] tile of [16 rA][32 q] shorts (1KB, wave-contiguous)
__global__ void k_wcat(const float* __restrict__ wrel, const float* __restrict__ wself,
                       short* __restrict__ wt) {
  int idx = blockIdx.x * 256 + threadIdx.x;
  if (idx >= 2 * NG * 8 * 512) return;
  int within = idx & 511;
  int tile = idx >> 9;
  int rA = within >> 5, q = within & 31;
  int nt8 = tile & 7;
  int lg = tile >> 3;
  int l = lg / NG, g = lg % NG;
  int n = nt8 * 16 + rA;
  int k = g * 32 + q;
  float v;
  if (k < N_REL * DIM) {
    int r = k >> 7, d = k & 127;
    v = wrel[(((size_t)l * N_REL + r) * DIM + d) * DIM + n];
  } else {
    int d = k - N_REL * DIM;
    v = wself[((size_t)l * DIM + d) * DIM + n];
  }
  wt[idx] = f2bf(v);
}

// ---------- fused layer, producer/consumer wave split ----------
// w0-3 produce per-(dst,rel) means into double-buffered As; w4-7 MFMA.
// Per relation: one 64B cnt load + one coalesced 256B slots load gives all 64
// edge srcs; empty segments (47%) skip their 4 h-row loads under a uniform branch.
__global__ __launch_bounds__(512, 4) void k_layer(const unsigned* __restrict__ hin,
                                                  const int* __restrict__ gcnt,
                                                  const int* __restrict__ slots,
                                                  const int* __restrict__ head,
                                                  const int* __restrict__ ovf_src,
                                                  const int* __restrict__ ovf_next,
                                                  const short* __restrict__ wt,
                                                  const unsigned* __restrict__ zrow,
                                                  unsigned* __restrict__ hout) {
  __shared__ unsigned As[2][BM][68];  // 272B row stride, double-buffered
  int t = threadIdx.x;
  int w = t >> 6, lane = t & 63;
  int row0 = blockIdx.x * BM;

  if (w < 4) {
    // ================= producer waves =================
    int pw = w;
    int seg = lane & 15, edge = lane >> 4;
    int segbase = row0 + pw * 16;               // this wave's first dst row
    int k0 = min(segbase + seg, NK - 1);        // it=0 key (rel 0)
    int cl  = gcnt[k0];                         // per-lane segment count
    int pfe = slots[(size_t)k0 * 4 + edge];     // per-lane edge src (slot 'edge')

    auto produce = [&](int buf, int it) {
      float invl = 1.0f / (float)(cl > 0 ? cl : 1);
      int invb = __builtin_bit_cast(int, invl);
      unsigned u0[16], u1[16], u2[16], u3[16];
      // phase 1: issue row loads; skip entirely-empty segments (uniform branch)
      #pragma unroll
      for (int j = 0; j < 16; ++j) {
        int cj = __builtin_amdgcn_readlane(cl, j);
        if (cj > 0) {
          int r0 = __builtin_amdgcn_readlane(pfe, j);
          int r1 = __builtin_amdgcn_readlane(pfe, j + 16);
          int r2 = __builtin_amdgcn_readlane(pfe, j + 32);
          int r3 = __builtin_amdgcn_readlane(pfe, j + 48);
          const unsigned* p1 = (cj > 1) ? hin + (size_t)r1 * 64 : zrow;
          const unsigned* p2 = (cj > 2) ? hin + (size_t)r2 * 64 : zrow;
          const unsigned* p3 = (cj > 3) ? hin + (size_t)r3 * 64 : zrow;
          u0[j] = hin[(size_t)r0 * 64 + lane];
          u1[j] = p1[lane];
          u2[j] = p2[lane];
          u3[j] = p3[lane];
        }
      }
      // prefetch next relation's counts + slots (overlaps accumulate+MFMA)
      int cl_n = 0, pfe_n = 0;
      if (it < 15) {
        int kn = min((it + 1) * N_NODES + segbase + seg, NK - 1);
        cl_n = gcnt[kn];
        pfe_n = slots[(size_t)kn * 4 + edge];
      }
      // fence: keep all loads above in flight; accumulate may not hoist
      __builtin_amdgcn_sched_barrier(0);
      // phase 2: accumulate -> As[buf]
      #pragma unroll
      for (int j = 0; j < 16; ++j) {
        int cj = __builtin_amdgcn_readlane(cl, j);
        if (cj == 0) {
          As[buf][pw * 16 + j][lane] = 0u;
        } else {
          float inv = __builtin_bit_cast(float, __builtin_amdgcn_readlane(invb, j));
          float s0 = bf_lo(u0[j]) + bf_lo(u1[j]) + bf_lo(u2[j]) + bf_lo(u3[j]);
          float s1 = bf_hi(u0[j]) + bf_hi(u1[j]) + bf_hi(u2[j]) + bf_hi(u3[j]);
          if (cj > 4) {                 // uniform, ~0.1% of segments: walk chain
            int kj = min(it * N_NODES + segbase + j, NK - 1);
            int cur = __builtin_amdgcn_readfirstlane(head[kj]);
            for (int x = 4; x < cj; ++x) {
              int sr = __builtin_amdgcn_readfirstlane(ovf_src[cur]);
              unsigned uu = hin[(size_t)sr * 64 + lane];
              s0 += bf_lo(uu); s1 += bf_hi(uu);
              cur = __builtin_amdgcn_readfirstlane(ovf_next[cur]);
            }
          }
          s0 *= inv; s1 *= inv;
          unsigned pk;
          asm("v_cvt_pk_bf16_f32 %0, %1, %2" : "=v"(pk) : "v"(s0), "v"(s1));  // RNE
          As[buf][pw * 16 + j][lane] = pk;
        }
      }
      cl = cl_n; pfe = pfe_n;
    };

    produce(0, 0);                      // fill buf0 for iteration 0
    __syncthreads();
    for (int it = 0; it < 17; ++it) {
      int nx = it + 1;
      if (nx < 16) {
        produce(nx & 1, nx);
      } else if (nx == 16) {            // self slot into buf (16&1)=0
        #pragma unroll
        for (int j = 0; j < 16; ++j) {
          int lr = min(segbase + j, N_NODES - 1);
          As[0][pw * 16 + j][lane] = hin[(size_t)lr * 64 + lane];
        }
      }
      __syncthreads();
    }
  } else {
    // ================= consumer waves =================
    int wid = w - 4, wm = wid >> 1, wn = wid & 1;   // (row-half, col-half)
    int quad = lane >> 4, rA = lane & 15;
    floatx4 acc[2][4];
    #pragma unroll
    for (int a = 0; a < 2; a++)
      #pragma unroll
      for (int b = 0; b < 4; b++) acc[a][b] = (floatx4)0.f;

    __syncthreads();
    for (int it = 0; it < 17; ++it) {
      int buf = it & 1;
      const short* arow0 = (const short*)&As[buf][wm * 32 + rA][0];
      const short* arow1 = (const short*)&As[buf][wm * 32 + 16 + rA][0];
      #pragma unroll
      for (int ks = 0; ks < 4; ++ks) {
        short8 a0 = *(const short8*)(arow0 + ks * 32 + quad * 8);
        short8 a1 = *(const short8*)(arow1 + ks * 32 + quad * 8);
        int kg = it * 4 + ks;
        const short* bp = wt + (size_t)(kg * 8 + wn * 4) * 512 + rA * 32 + quad * 8;
        #pragma unroll
        for (int nt = 0; nt < 4; ++nt) {
          short8 b = *(const short8*)(bp + nt * 512);  // 1KB tile, L2-hot
          acc[0][nt] = __builtin_amdgcn_mfma_f32_16x16x32_bf16(a0, b, acc[0][nt], 0, 0, 0);
          acc[1][nt] = __builtin_amdgcn_mfma_f32_16x16x32_bf16(a1, b, acc[1][nt], 0, 0, 0);
        }
      }
      __syncthreads();
    }
    // epilogue: C row=(lane>>4)*4+j, col=lane&15 within each 16x16 tile
    #pragma unroll
    for (int mt = 0; mt < 2; ++mt)
      #pragma unroll
      for (int nt = 0; nt < 4; ++nt)
        #pragma unroll
        for (int j = 0; j < 4; ++j) {
          int row = row0 + wm * 32 + mt * 16 + quad * 4 + j;
          int col = wn * 64 + nt * 16 + rA;
          if (row < N_NODES)
            ((short*)hout)[(size_t)row * DIM + col] = f2bf(fmaxf(acc[mt][nt][j], 0.f));
        }
  }
}

// ---------- scoring (bf16 h) ----------
__global__ void k_score(const unsigned* __restrict__ h, const int* __restrict__ heads,
                        const int* __restrict__ rels, const int* __restrict__ tails,
                        const float* __restrict__ rel_emb, const float* __restrict__ path_feat,
                        const int* __restrict__ task_idx, const float* __restrict__ delta_w,
                        const float* __restrict__ lambda_logit, const float* __restrict__ rule_init,
                        float* __restrict__ out) {
  int q = (blockIdx.x * 256 + threadIdx.x) >> 6;
  int lane = threadIdx.x & 63;
  int hd = heads[q], tl = tails[q], rl = rels[q];
  unsigned ua = h[(size_t)hd * 64 + lane];
  unsigned uc = h[(size_t)tl * 64 + lane];
  float2 r = *(const float2*)(rel_emb + (size_t)rl * DIM + lane * 2);
  float s = bf_lo(ua) * r.x * bf_lo(uc) + bf_hi(ua) * r.y * bf_hi(uc);
  #pragma unroll
  for (int off = 32; off; off >>= 1) s += __shfl_xor(s, off, 64);
  if (lane == 0) {
    int task = task_idx[0];
    float sp = 0.f;
    #pragma unroll
    for (int p = 0; p < PATH_DIM; p++)
      sp += path_feat[q * PATH_DIM + p] *
            (rule_init[task * PATH_DIM + p] + delta_w[task * PATH_DIM + p]);
    float lam = 1.f / (1.f + __expf(-lambda_logit[task]));
    out[q] = lam * s + (1.f - lam) * sp;
  }
}

extern "C" void kernel_launch(void* const* d_in, const int* in_sizes, int n_in,
                              void* d_out, int out_size, void* d_ws, size_t ws_size,
                              hipStream_t stream) {
  const int*   node_ids   = (const int*)d_in[0];
  const int*   edge_index = (const int*)d_in[1];
  const int*   edge_type  = (const int*)d_in[2];
  const int*   heads      = (const int*)d_in[3];
  const int*   rels       = (const int*)d_in[4];
  const int*   tails      = (const int*)d_in[5];
  const float* path_feat  = (const float*)d_in[6];
  const int*   task_idx   = (const int*)d_in[7];
  const float* entity_emb = (const float*)d_in[8];
  const float* rel_emb    = (const float*)d_in[9];
  const float* W_self     = (const float*)d_in[10];
  const float* W_rel      = (const float*)d_in[11];
  const float* delta_w    = (const float*)d_in[12];
  const float* lambda_lg  = (const float*)d_in[13];
  const float* rule_init  = (const float*)d_in[14];

  char* ws = (char*)d_ws;
  size_t off = 0;
  auto alloc = [&](size_t bytes) -> void* {
    void* p = ws + off;
    off = (off + bytes + 255) & ~(size_t)255;
    return p;
  };
  unsigned* h_a    = (unsigned*)alloc((size_t)N_NODES * DIM * 2);
  unsigned* h_b    = (unsigned*)alloc((size_t)N_NODES * DIM * 2);
  short*    wt     = (short*)alloc((size_t)2 * NG * 8 * 512 * 2);
  int*      zreg   = (int*)alloc((size_t)(2 * NK + 64) * 4);  // cnt | head | cursor
  int*      cntA   = zreg;
  int*      headA  = zreg + NK;
  int*      cursor = zreg + 2 * NK;
  int*      slots  = (int*)alloc((size_t)NK * 4 * 4);
  int*      ovf_s  = (int*)alloc((size_t)(E_EDGES + 2) * 4);
  int*      ovf_n  = (int*)alloc((size_t)(E_EDGES + 2) * 4);
  unsigned* zrow   = (unsigned*)alloc(256);

  hipMemsetAsync(zreg, 0, (size_t)(2 * NK + 64) * 4, stream);
  hipMemsetAsync(zrow, 0, 256, stream);
  int eb = (E_EDGES + 255) / 256;
  k_bucket<<<eb, 256, 0, stream>>>(edge_index, edge_type, cntA, headA, cursor,
                                   slots, ovf_s, ovf_n);
  k_h0<<<(N_NODES * 32) / 256, 256, 0, stream>>>(node_ids, entity_emb, h_a);
  k_wcat<<<(2 * NG * 8 * 512 + 255) / 256, 256, 0, stream>>>(W_rel, W_self, wt);

  const unsigned* hin = h_a;
  unsigned* hout = h_b;
  int nblk = (N_NODES + BM - 1) / BM;
  for (int l = 0; l < 2; l++) {
    k_layer<<<nblk, 512, 0, stream>>>(hin, cntA, slots, headA, ovf_s, ovf_n,
                                      wt + (size_t)l * NG * 8 * 512, zrow, hout);
    const unsigned* tmp = hout;
    hout = (unsigned*)hin;
    hin = tmp;
  }
  k_score<<<NQ / 4, 256, 0, stream>>>(hin, heads, rels, tails, rel_emb, path_feat,
                                      task_idx, delta_w, lambda_lg, rule_init,
                                      (float*)d_out);
}